// Round 15
// baseline (223.780 us; speedup 1.0000x reference)
//
#include <hip/hip_runtime.h>

constexpr int N_NODES  = 100000;
constexpr int N_EDGES  = 1200000;
constexpr int N_GRAPHS = 1000;
constexpr int DIM      = 64;
constexpr int ODIM     = 32;
constexpr int MAXD     = 10;

// coarse binning (two-level CSR build, R11-proven)
constexpr int NPB   = 512;
constexpr int NBUK  = (N_NODES + NPB - 1) / NPB;  // 196
constexpr int CAP   = 8192;
constexpr int EPB   = 4096;
constexpr int P1_NB = (N_EDGES + EPB - 1) / EPB;  // 293

// degree-ordering buckets for conv
constexpr int NBKT     = 32;
constexpr int BPAD     = 32;
constexpr int LIST_PAD = N_NODES + NBKT * (BPAD - 1);  // 100992
constexpr int CONV_BLK = LIST_PAD / BPAD;              // 3156

typedef float v2f __attribute__((ext_vector_type(2)));

// ---------------------------------------------------------------------------
// prep: fused init (bcur/gcount/nodelist) + x f32 -> fp8 table (HW cvt)
// ---------------------------------------------------------------------------
constexpr int PREP_THREADS = N_NODES * DIM / 8;   // 800000
__global__ void prep_kernel(const float* __restrict__ x,
                            unsigned char* __restrict__ xq,
                            int* __restrict__ bcur, int* __restrict__ gcount,
                            int* __restrict__ nodelist) {
    int i = blockIdx.x * 256 + threadIdx.x;
    if (i < LIST_PAD) nodelist[i] = -1;
    if (i < NBUK) bcur[i] = 0;
    if (i < NBKT) gcount[i] = 0;
    if (i < PREP_THREADS) {
        const float4 v0 = *reinterpret_cast<const float4*>(x + (size_t)i * 8);
        const float4 v1 = *reinterpret_cast<const float4*>(x + (size_t)i * 8 + 4);
        int lo = __builtin_amdgcn_cvt_pk_fp8_f32(v0.x, v0.y, 0, false);
        lo = __builtin_amdgcn_cvt_pk_fp8_f32(v0.z, v0.w, lo, true);
        int hi = __builtin_amdgcn_cvt_pk_fp8_f32(v1.x, v1.y, 0, false);
        hi = __builtin_amdgcn_cvt_pk_fp8_f32(v1.z, v1.w, hi, true);
        uint2 o; o.x = (unsigned)lo; o.y = (unsigned)hi;
        *reinterpret_cast<uint2*>(xq + (size_t)i * 8) = o;
    }
}

// ---------------------------------------------------------------------------
// pass1: block counting-sort of EPB edges into NBUK coarse buckets (R11)
// ---------------------------------------------------------------------------
__global__ __launch_bounds__(256) void pass1_bin_kernel(const int* __restrict__ src,
                                                        const int* __restrict__ dst,
                                                        int* __restrict__ bcur,
                                                        int* __restrict__ pairs) {
    __shared__ int hist[NBUK];
    __shared__ int sexcl[NBUK];
    __shared__ int bbase[NBUK];
    __shared__ int sc[256];
    __shared__ int buf[EPB];
    __shared__ unsigned char bid[EPB];
    int t = threadIdx.x;
    for (int i = t; i < NBUK; i += 256) hist[i] = 0;
    __syncthreads();

    int e0 = blockIdx.x * EPB;
    int cnt = min(EPB, N_EDGES - e0);

    int pk[16], pb[16], pr[16];
#pragma unroll
    for (int k = 0; k < 16; ++k) {
        int j = t + k * 256;
        pb[k] = -1;
        if (j < cnt) {
            int s = src[e0 + j];
            int d = dst[e0 + j];
            int b = d >> 9;
            pb[k] = b;
            pk[k] = s | ((d & (NPB - 1)) << 17);
            pr[k] = atomicAdd(&hist[b], 1);
        }
    }
    __syncthreads();

    int v = (t < NBUK) ? hist[t] : 0;
    sc[t] = v;
    __syncthreads();
    for (int off = 1; off < 256; off <<= 1) {
        int u = (t >= off) ? sc[t - off] : 0;
        __syncthreads();
        sc[t] += u;
        __syncthreads();
    }
    if (t < NBUK) {
        sexcl[t] = sc[t] - v;
        bbase[t] = v ? atomicAdd(&bcur[t], v) : 0;
    }
    __syncthreads();

#pragma unroll
    for (int k = 0; k < 16; ++k) {
        if (pb[k] >= 0) {
            int pos = sexcl[pb[k]] + pr[k];
            buf[pos] = pk[k];
            bid[pos] = (unsigned char)pb[k];
        }
    }
    __syncthreads();

#pragma unroll
    for (int k = 0; k < 16; ++k) {
        int j = t + k * 256;
        if (j < cnt) {
            int b = bid[j];
            pairs[(size_t)b * CAP + bbase[b] + (j - sexcl[b])] = buf[j];
        }
    }
}

// ---------------------------------------------------------------------------
// escan: exclusive scan of bucket counts -> ebase; rowptr[N]=E
// ---------------------------------------------------------------------------
__global__ void escan_kernel(const int* __restrict__ bcur, int* __restrict__ ebase,
                             int* __restrict__ rowptr) {
    __shared__ int sc[256];
    int t = threadIdx.x;
    int v = (t < NBUK) ? bcur[t] : 0;
    sc[t] = v;
    __syncthreads();
    for (int off = 1; off < 256; off <<= 1) {
        int u = (t >= off) ? sc[t - off] : 0;
        __syncthreads();
        sc[t] += u;
        __syncthreads();
    }
    if (t < NBUK) ebase[t] = sc[t] - v;
    if (t == NBUK - 1) ebase[NBUK] = sc[t];
    if (t == 0) rowptr[N_NODES] = N_EDGES;
}

// ---------------------------------------------------------------------------
// pass2: one block per coarse bucket: deg/rowptr writeout + csr scatter (R11)
// ---------------------------------------------------------------------------
__global__ __launch_bounds__(256) void pass2_kernel(const int* __restrict__ pairs,
                                                    const int* __restrict__ bcnt,
                                                    const int* __restrict__ ebase,
                                                    int* __restrict__ deg,
                                                    int* __restrict__ rowptr,
                                                    int* __restrict__ csr,
                                                    int* __restrict__ gcount) {
    __shared__ int dh[NPB];
    __shared__ int sc[256];
    __shared__ int gh[NBKT];
    int b = blockIdx.x, t = threadIdx.x;
    int nbeg = b * NPB;
    int nn = min(NPB, N_NODES - nbeg);
    int cnt = bcnt[b];
    int base = ebase[b];
    const int* reg = pairs + (size_t)b * CAP;

    for (int i = t; i < NPB; i += 256) dh[i] = 0;
    if (t < NBKT) gh[t] = 0;
    __syncthreads();

    for (int j = t; j < cnt; j += 256)
        atomicAdd(&dh[reg[j] >> 17], 1);
    __syncthreads();

    int a0 = dh[2 * t];
    int a1 = dh[2 * t + 1];
    sc[t] = a0 + a1;
    __syncthreads();
    for (int off = 1; off < 256; off <<= 1) {
        int u = (t >= off) ? sc[t - off] : 0;
        __syncthreads();
        sc[t] += u;
        __syncthreads();
    }
    int e0 = sc[t] - (a0 + a1);
    int e1 = e0 + a0;
    int i0 = 2 * t, i1 = 2 * t + 1;
    if (i0 < nn) {
        deg[nbeg + i0] = a0;
        rowptr[nbeg + i0] = base + e0;
        atomicAdd(&gh[min(a0, NBKT - 1)], 1);
    }
    if (i1 < nn) {
        deg[nbeg + i1] = a1;
        rowptr[nbeg + i1] = base + e1;
        atomicAdd(&gh[min(a1, NBKT - 1)], 1);
    }
    __syncthreads();
    dh[i0] = e0;
    dh[i1] = e1;
    __syncthreads();

    for (int j = t; j < cnt; j += 256) {
        int p = reg[j];
        int r = atomicAdd(&dh[p >> 17], 1);
        csr[base + r] = p & 0x1FFFF;
    }
    __syncthreads();
    if (t < NBKT && gh[t]) atomicAdd(&gcount[t], gh[t]);
}

// ---------------------------------------------------------------------------
// gscan + bucket scatter (R11)
// ---------------------------------------------------------------------------
__global__ void gscan_kernel(const int* __restrict__ gcount, int* __restrict__ gcur) {
    if (threadIdx.x == 0) {
        int off = 0;
        for (int k = 0; k < NBKT; ++k) {
            gcur[k] = off;
            off += (gcount[k] + BPAD - 1) & ~(BPAD - 1);
        }
    }
}

__global__ void bucket_scatter_kernel(const int* __restrict__ deg,
                                      int* __restrict__ gcur,
                                      int* __restrict__ nodelist) {
    __shared__ int lh[NBKT], lbase[NBKT];
    int t = threadIdx.x;
    if (t < NBKT) lh[t] = 0;
    __syncthreads();
    int i = blockIdx.x * 256 + t;
    int k = 0, r = 0;
    bool valid = (i < N_NODES);
    if (valid) {
        k = min(deg[i], NBKT - 1);
        r = atomicAdd(&lh[k], 1);
    }
    __syncthreads();
    if (t < NBKT && lh[t]) lbase[t] = atomicAdd(&gcur[t], lh[t]);
    __syncthreads();
    if (valid) nodelist[lbase[k] + r] = i;
}

// ---------------------------------------------------------------------------
// Shared conv body: fp8 gather with 16B/lane PAIRED loads (2 edges per
// 8-lane group per step -> 2x rows in flight) + bucketed matvec.
// Gather group = 8 lanes: sub = q>>2 picks edge parity, part = q&3 picks
// the 16B quarter of the 64B row. Cross-sub reduce via shfl_xor(4).
// OUTMODE 0: write f32 rows to outf (emb).
// OUTMODE 1: relu + HW fp8 encode -> outq (table for conv2).
// ---------------------------------------------------------------------------
template <int OUTMODE>
__global__ __launch_bounds__(256) void conv_fp8_kernel(
        const unsigned char* __restrict__ xq,
        const int* __restrict__ rowptr,
        const int* __restrict__ csr,
        const int* __restrict__ nodelist,
        const float* __restrict__ Wl,
        const float* __restrict__ bl,
        const float* __restrict__ Wr,
        float* __restrict__ outf,
        unsigned char* __restrict__ outq) {
    __shared__ float lds_h[BPAD][DIM + 4];
    __shared__ float lds_x[BPAD][DIM + 4];
    __shared__ int s_node[BPAD];
    __shared__ int s_d0;

    int base = blockIdx.x * BPAD;
    int node0 = nodelist[base];
    if (node0 < 0) return;

    int grp  = threadIdx.x >> 3;   // 0..31 node slot
    int q    = threadIdx.x & 7;
    int sub  = q >> 2;             // edge parity (0/1)
    int part = q & 3;              // 16B quarter of row
    int node = nodelist[base + grp];
    bool valid = (node >= 0);

    int beg = 0, end = 0;
    if (valid) { beg = rowptr[node]; end = rowptr[node + 1]; }

    if (threadIdx.x == 0) s_d0 = min(end - beg, MAXD);
    if (q == 0) s_node[grp] = node;

    float hs[16];
#pragma unroll
    for (int j = 0; j < 16; ++j) hs[j] = 0.f;

#define QACC16(a) { \
    v2f p; \
    p = __builtin_amdgcn_cvt_pk_f32_fp8((a).x, false); hs[0] += p.x;  hs[1] += p.y; \
    p = __builtin_amdgcn_cvt_pk_f32_fp8((a).x, true);  hs[2] += p.x;  hs[3] += p.y; \
    p = __builtin_amdgcn_cvt_pk_f32_fp8((a).y, false); hs[4] += p.x;  hs[5] += p.y; \
    p = __builtin_amdgcn_cvt_pk_f32_fp8((a).y, true);  hs[6] += p.x;  hs[7] += p.y; \
    p = __builtin_amdgcn_cvt_pk_f32_fp8((a).z, false); hs[8] += p.x;  hs[9] += p.y; \
    p = __builtin_amdgcn_cvt_pk_f32_fp8((a).z, true);  hs[10] += p.x; hs[11] += p.y; \
    p = __builtin_amdgcn_cvt_pk_f32_fp8((a).w, false); hs[12] += p.x; hs[13] += p.y; \
    p = __builtin_amdgcn_cvt_pk_f32_fp8((a).w, true);  hs[14] += p.x; hs[15] += p.y; }

    int e = beg;
    // main: 16 edges per iteration (8 per sub-lane, stride 2)
    for (; e + 16 <= end; e += 16) {
        int s0 = csr[e + sub + 0],  s1 = csr[e + sub + 2];
        int s2 = csr[e + sub + 4],  s3 = csr[e + sub + 6];
        int s4 = csr[e + sub + 8],  s5 = csr[e + sub + 10];
        int s6 = csr[e + sub + 12], s7 = csr[e + sub + 14];
        uint4 a0 = *reinterpret_cast<const uint4*>(xq + (size_t)s0 * DIM + part * 16);
        uint4 a1 = *reinterpret_cast<const uint4*>(xq + (size_t)s1 * DIM + part * 16);
        uint4 a2 = *reinterpret_cast<const uint4*>(xq + (size_t)s2 * DIM + part * 16);
        uint4 a3 = *reinterpret_cast<const uint4*>(xq + (size_t)s3 * DIM + part * 16);
        uint4 a4 = *reinterpret_cast<const uint4*>(xq + (size_t)s4 * DIM + part * 16);
        uint4 a5 = *reinterpret_cast<const uint4*>(xq + (size_t)s5 * DIM + part * 16);
        uint4 a6 = *reinterpret_cast<const uint4*>(xq + (size_t)s6 * DIM + part * 16);
        uint4 a7 = *reinterpret_cast<const uint4*>(xq + (size_t)s7 * DIM + part * 16);
        QACC16(a0) QACC16(a1) QACC16(a2) QACC16(a3)
        QACC16(a4) QACC16(a5) QACC16(a6) QACC16(a7)
    }
    // paired tail: 2 edges per step
    for (; e + 2 <= end; e += 2) {
        int s = csr[e + sub];
        uint4 a = *reinterpret_cast<const uint4*>(xq + (size_t)s * DIM + part * 16);
        QACC16(a)
    }
    // odd final edge: sub==0 lanes only
    if (e < end && sub == 0) {
        int s = csr[e];
        uint4 a = *reinterpret_cast<const uint4*>(xq + (size_t)s * DIM + part * 16);
        QACC16(a)
    }

    // reduce the two edge-parity partial sums: lane q <-> q^4
#pragma unroll
    for (int j = 0; j < 16; ++j) hs[j] += __shfl_xor(hs[j], 4);

    // self row + LDS staging (sub==0 lanes hold the reduced sums)
    if (sub == 0) {
        float xv[16];
        if (valid) {
            uint4 a = *reinterpret_cast<const uint4*>(xq + (size_t)node * DIM + part * 16);
            v2f p;
            p = __builtin_amdgcn_cvt_pk_f32_fp8(a.x, false); xv[0] = p.x;  xv[1] = p.y;
            p = __builtin_amdgcn_cvt_pk_f32_fp8(a.x, true);  xv[2] = p.x;  xv[3] = p.y;
            p = __builtin_amdgcn_cvt_pk_f32_fp8(a.y, false); xv[4] = p.x;  xv[5] = p.y;
            p = __builtin_amdgcn_cvt_pk_f32_fp8(a.y, true);  xv[6] = p.x;  xv[7] = p.y;
            p = __builtin_amdgcn_cvt_pk_f32_fp8(a.z, false); xv[8] = p.x;  xv[9] = p.y;
            p = __builtin_amdgcn_cvt_pk_f32_fp8(a.z, true);  xv[10] = p.x; xv[11] = p.y;
            p = __builtin_amdgcn_cvt_pk_f32_fp8(a.w, false); xv[12] = p.x; xv[13] = p.y;
            p = __builtin_amdgcn_cvt_pk_f32_fp8(a.w, true);  xv[14] = p.x; xv[15] = p.y;
        } else {
#pragma unroll
            for (int j = 0; j < 16; ++j) xv[j] = 0.f;
        }
        int d0off = part * 16;
        *reinterpret_cast<float4*>(&lds_h[grp][d0off + 0])  = make_float4(hs[0], hs[1], hs[2], hs[3]);
        *reinterpret_cast<float4*>(&lds_h[grp][d0off + 4])  = make_float4(hs[4], hs[5], hs[6], hs[7]);
        *reinterpret_cast<float4*>(&lds_h[grp][d0off + 8])  = make_float4(hs[8], hs[9], hs[10], hs[11]);
        *reinterpret_cast<float4*>(&lds_h[grp][d0off + 12]) = make_float4(hs[12], hs[13], hs[14], hs[15]);
        *reinterpret_cast<float4*>(&lds_x[grp][d0off + 0])  = make_float4(xv[0], xv[1], xv[2], xv[3]);
        *reinterpret_cast<float4*>(&lds_x[grp][d0off + 4])  = make_float4(xv[4], xv[5], xv[6], xv[7]);
        *reinterpret_cast<float4*>(&lds_x[grp][d0off + 8])  = make_float4(xv[8], xv[9], xv[10], xv[11]);
        *reinterpret_cast<float4*>(&lds_x[grp][d0off + 12]) = make_float4(xv[12], xv[13], xv[14], xv[15]);
    }
#undef QACC16
    __syncthreads();

    int mgrp = threadIdx.x >> 4;
    int mq   = threadIdx.x & 15;
    int d0 = s_d0;
    const float* wl = Wl + (size_t)d0 * DIM * DIM + mq * 4;
    const float* wr = Wr + (size_t)d0 * DIM * DIM + mq * 4;
    float4 accA = *reinterpret_cast<const float4*>(bl + d0 * DIM + mq * 4);
    float4 accB = accA;

#pragma unroll 8
    for (int i = 0; i < DIM; ++i) {
        float4 wlv = *reinterpret_cast<const float4*>(wl + i * DIM);
        float4 wrv = *reinterpret_cast<const float4*>(wr + i * DIM);
        float hA = lds_h[mgrp][i],      xA = lds_x[mgrp][i];
        float hB = lds_h[mgrp + 16][i], xB = lds_x[mgrp + 16][i];
        accA.x += hA * wlv.x + xA * wrv.x;
        accA.y += hA * wlv.y + xA * wrv.y;
        accA.z += hA * wlv.z + xA * wrv.z;
        accA.w += hA * wlv.w + xA * wrv.w;
        accB.x += hB * wlv.x + xB * wrv.x;
        accB.y += hB * wlv.y + xB * wrv.y;
        accB.z += hB * wlv.z + xB * wrv.z;
        accB.w += hB * wlv.w + xB * wrv.w;
    }

    int nodeA = s_node[mgrp];
    int nodeB = s_node[mgrp + 16];
    if (OUTMODE == 0) {
        if (nodeA >= 0)
            *reinterpret_cast<float4*>(outf + (size_t)nodeA * DIM + mq * 4) = accA;
        if (nodeB >= 0)
            *reinterpret_cast<float4*>(outf + (size_t)nodeB * DIM + mq * 4) = accB;
    } else {
        if (nodeA >= 0) {
            int oq = __builtin_amdgcn_cvt_pk_fp8_f32(fmaxf(accA.x, 0.f), fmaxf(accA.y, 0.f), 0, false);
            oq = __builtin_amdgcn_cvt_pk_fp8_f32(fmaxf(accA.z, 0.f), fmaxf(accA.w, 0.f), oq, true);
            *reinterpret_cast<unsigned*>(outq + (size_t)nodeA * DIM + mq * 4) = (unsigned)oq;
        }
        if (nodeB >= 0) {
            int oq = __builtin_amdgcn_cvt_pk_fp8_f32(fmaxf(accB.x, 0.f), fmaxf(accB.y, 0.f), 0, false);
            oq = __builtin_amdgcn_cvt_pk_fp8_f32(fmaxf(accB.z, 0.f), fmaxf(accB.w, 0.f), oq, true);
            *reinterpret_cast<unsigned*>(outq + (size_t)nodeB * DIM + mq * 4) = (unsigned)oq;
        }
    }
}

// ---------------------------------------------------------------------------
// Fused global_add_pool(relu(emb)) + MLP head; one block per graph.
// ---------------------------------------------------------------------------
__global__ void pool_head_kernel(const float* __restrict__ emb,
                                 const int* __restrict__ batch,
                                 const float* __restrict__ W1,
                                 const float* __restrict__ b1,
                                 const float* __restrict__ W2,
                                 const float* __restrict__ b2,
                                 float* __restrict__ pred) {
    __shared__ float red[4][DIM];
    __shared__ float garr[DIM];
    __shared__ float hid[DIM];
    int gi = blockIdx.x;
    int w = threadIdx.x >> 6;
    int lane = threadIdx.x & 63;

    int lo = 0, hi = N_NODES;
    while (lo < hi) { int mid = (lo + hi) >> 1; if (batch[mid] < gi) lo = mid + 1; else hi = mid; }
    int beg = lo;
    hi = N_NODES;
    while (lo < hi) { int mid = (lo + hi) >> 1; if (batch[mid] < gi + 1) lo = mid + 1; else hi = mid; }
    int end = lo;

    float acc = 0.f;
    for (int n = beg + w; n < end; n += 4)
        acc += fmaxf(emb[(size_t)n * DIM + lane], 0.f);
    red[w][lane] = acc;
    __syncthreads();
    if (w == 0)
        garr[lane] = red[0][lane] + red[1][lane] + red[2][lane] + red[3][lane];
    __syncthreads();

    if (threadIdx.x < DIM) {
        int o = threadIdx.x;
        float a = b1[o];
#pragma unroll 8
        for (int i = 0; i < DIM; ++i) a += garr[i] * W1[i * DIM + o];
        hid[o] = a;
    }
    __syncthreads();
    if (threadIdx.x < ODIM) {
        int o = threadIdx.x;
        float p = b2[o];
#pragma unroll 8
        for (int i = 0; i < DIM; ++i) p += hid[i] * W2[i * ODIM + o];
        pred[(size_t)gi * ODIM + o] = p;
    }
}

extern "C" void kernel_launch(void* const* d_in, const int* in_sizes, int n_in,
                              void* d_out, int out_size, void* d_ws, size_t ws_size,
                              hipStream_t stream) {
    const float* x    = (const float*)d_in[0];
    const int* eidx   = (const int*)d_in[1];
    const int* src    = eidx;
    const int* dst    = eidx + N_EDGES;
    const int* batch  = (const int*)d_in[2];
    const float* Wl1  = (const float*)d_in[4];
    const float* bl1  = (const float*)d_in[5];
    const float* Wr1  = (const float*)d_in[6];
    const float* Wl2  = (const float*)d_in[7];
    const float* bl2  = (const float*)d_in[8];
    const float* Wr2  = (const float*)d_in[9];
    const float* W1   = (const float*)d_in[10];
    const float* b1   = (const float*)d_in[11];
    const float* W2   = (const float*)d_in[12];
    const float* b2   = (const float*)d_in[13];

    float* emb  = (float*)d_out;                          // [N_NODES, 64]
    float* pred = (float*)d_out + (size_t)N_NODES * DIM;  // [N_GRAPHS, 32]

    // Workspace
    int* bcur     = (int*)d_ws;                  // [256]
    int* ebase    = bcur + 256;                  // [256]
    int* gcount   = ebase + 256;                 // [32]
    int* gcur     = gcount + NBKT;               // [32]
    int* deg      = gcur + NBKT;                 // [100000]
    int* rowptr   = deg + N_NODES;               // [100004]
    int* nodelist = rowptr + N_NODES + 4;        // [100992]
    int* csr      = nodelist + LIST_PAD;         // [1200000]
    int* pairs    = csr + N_EDGES;               // [196*8192]
    unsigned char* xq = (unsigned char*)(pairs + NBUK * CAP);    // [N*64] fp8
    unsigned char* hq = xq + (size_t)N_NODES * DIM;              // [N*64] fp8

    prep_kernel<<<(PREP_THREADS + 255) / 256, 256, 0, stream>>>(x, xq, bcur, gcount, nodelist);
    pass1_bin_kernel<<<P1_NB, 256, 0, stream>>>(src, dst, bcur, pairs);
    escan_kernel<<<1, 256, 0, stream>>>(bcur, ebase, rowptr);
    pass2_kernel<<<NBUK, 256, 0, stream>>>(pairs, bcur, ebase, deg, rowptr, csr, gcount);
    gscan_kernel<<<1, 64, 0, stream>>>(gcount, gcur);
    bucket_scatter_kernel<<<(N_NODES + 255) / 256, 256, 0, stream>>>(deg, gcur, nodelist);

    // conv1: fp8 paired gather + matvec + relu -> hq (fp8 table for conv2)
    conv_fp8_kernel<1><<<CONV_BLK, 256, 0, stream>>>(xq, rowptr, csr, nodelist,
                                                     Wl1, bl1, Wr1, nullptr, hq);
    // conv2: fp8 paired gather + matvec -> emb (f32, pre-activation output)
    conv_fp8_kernel<0><<<CONV_BLK, 256, 0, stream>>>(hq, rowptr, csr, nodelist,
                                                     Wl2, bl2, Wr2, emb, nullptr);
    // fused pool + head
    pool_head_kernel<<<N_GRAPHS, 256, 0, stream>>>(emb, batch, W1, b1, W2, b2, pred);
}

// Round 16
// 221.420 us; speedup vs baseline: 1.0107x; 1.0107x over previous
//
#include <hip/hip_runtime.h>

constexpr int N_NODES  = 100000;
constexpr int N_EDGES  = 1200000;
constexpr int N_GRAPHS = 1000;
constexpr int DIM      = 64;
constexpr int ODIM     = 32;
constexpr int MAXD     = 10;

// coarse binning (two-level CSR build, R11-proven)
constexpr int NPB   = 512;
constexpr int NBUK  = (N_NODES + NPB - 1) / NPB;  // 196
constexpr int CAP   = 8192;
constexpr int EPB   = 4096;
constexpr int P1_NB = (N_EDGES + EPB - 1) / EPB;  // 293

// degree-ordering buckets for conv
constexpr int NBKT     = 32;
constexpr int BPAD     = 32;
constexpr int LIST_PAD = N_NODES + NBKT * (BPAD - 1);  // 100992
constexpr int CONV_BLK = LIST_PAD / BPAD;              // 3156

typedef float v2f __attribute__((ext_vector_type(2)));

// ---------------------------------------------------------------------------
// prep: fused init (bcur/gcount/nodelist) + x f32 -> fp8 table (HW cvt)
// ---------------------------------------------------------------------------
constexpr int PREP_THREADS = N_NODES * DIM / 8;   // 800000
__global__ void prep_kernel(const float* __restrict__ x,
                            unsigned char* __restrict__ xq,
                            int* __restrict__ bcur, int* __restrict__ gcount,
                            int* __restrict__ nodelist) {
    int i = blockIdx.x * 256 + threadIdx.x;
    if (i < LIST_PAD) nodelist[i] = -1;
    if (i < NBUK) bcur[i] = 0;
    if (i < NBKT) gcount[i] = 0;
    if (i < PREP_THREADS) {
        const float4 v0 = *reinterpret_cast<const float4*>(x + (size_t)i * 8);
        const float4 v1 = *reinterpret_cast<const float4*>(x + (size_t)i * 8 + 4);
        int lo = __builtin_amdgcn_cvt_pk_fp8_f32(v0.x, v0.y, 0, false);
        lo = __builtin_amdgcn_cvt_pk_fp8_f32(v0.z, v0.w, lo, true);
        int hi = __builtin_amdgcn_cvt_pk_fp8_f32(v1.x, v1.y, 0, false);
        hi = __builtin_amdgcn_cvt_pk_fp8_f32(v1.z, v1.w, hi, true);
        uint2 o; o.x = (unsigned)lo; o.y = (unsigned)hi;
        *reinterpret_cast<uint2*>(xq + (size_t)i * 8) = o;
    }
}

// ---------------------------------------------------------------------------
// pass1: block counting-sort of EPB edges into NBUK coarse buckets (R11)
// ---------------------------------------------------------------------------
__global__ __launch_bounds__(256) void pass1_bin_kernel(const int* __restrict__ src,
                                                        const int* __restrict__ dst,
                                                        int* __restrict__ bcur,
                                                        int* __restrict__ pairs) {
    __shared__ int hist[NBUK];
    __shared__ int sexcl[NBUK];
    __shared__ int bbase[NBUK];
    __shared__ int sc[256];
    __shared__ int buf[EPB];
    __shared__ unsigned char bid[EPB];
    int t = threadIdx.x;
    for (int i = t; i < NBUK; i += 256) hist[i] = 0;
    __syncthreads();

    int e0 = blockIdx.x * EPB;
    int cnt = min(EPB, N_EDGES - e0);

    int pk[16], pb[16], pr[16];
#pragma unroll
    for (int k = 0; k < 16; ++k) {
        int j = t + k * 256;
        pb[k] = -1;
        if (j < cnt) {
            int s = src[e0 + j];
            int d = dst[e0 + j];
            int b = d >> 9;
            pb[k] = b;
            pk[k] = s | ((d & (NPB - 1)) << 17);
            pr[k] = atomicAdd(&hist[b], 1);
        }
    }
    __syncthreads();

    int v = (t < NBUK) ? hist[t] : 0;
    sc[t] = v;
    __syncthreads();
    for (int off = 1; off < 256; off <<= 1) {
        int u = (t >= off) ? sc[t - off] : 0;
        __syncthreads();
        sc[t] += u;
        __syncthreads();
    }
    if (t < NBUK) {
        sexcl[t] = sc[t] - v;
        bbase[t] = v ? atomicAdd(&bcur[t], v) : 0;
    }
    __syncthreads();

#pragma unroll
    for (int k = 0; k < 16; ++k) {
        if (pb[k] >= 0) {
            int pos = sexcl[pb[k]] + pr[k];
            buf[pos] = pk[k];
            bid[pos] = (unsigned char)pb[k];
        }
    }
    __syncthreads();

#pragma unroll
    for (int k = 0; k < 16; ++k) {
        int j = t + k * 256;
        if (j < cnt) {
            int b = bid[j];
            pairs[(size_t)b * CAP + bbase[b] + (j - sexcl[b])] = buf[j];
        }
    }
}

// ---------------------------------------------------------------------------
// escan: exclusive scan of bucket counts -> ebase; rowptr[N]=E
// ---------------------------------------------------------------------------
__global__ void escan_kernel(const int* __restrict__ bcur, int* __restrict__ ebase,
                             int* __restrict__ rowptr) {
    __shared__ int sc[256];
    int t = threadIdx.x;
    int v = (t < NBUK) ? bcur[t] : 0;
    sc[t] = v;
    __syncthreads();
    for (int off = 1; off < 256; off <<= 1) {
        int u = (t >= off) ? sc[t - off] : 0;
        __syncthreads();
        sc[t] += u;
        __syncthreads();
    }
    if (t < NBUK) ebase[t] = sc[t] - v;
    if (t == NBUK - 1) ebase[NBUK] = sc[t];
    if (t == 0) rowptr[N_NODES] = N_EDGES;
}

// ---------------------------------------------------------------------------
// pass2: one block per coarse bucket: deg/rowptr writeout + csr scatter (R11)
// ---------------------------------------------------------------------------
__global__ __launch_bounds__(256) void pass2_kernel(const int* __restrict__ pairs,
                                                    const int* __restrict__ bcnt,
                                                    const int* __restrict__ ebase,
                                                    int* __restrict__ deg,
                                                    int* __restrict__ rowptr,
                                                    int* __restrict__ csr,
                                                    int* __restrict__ gcount) {
    __shared__ int dh[NPB];
    __shared__ int sc[256];
    __shared__ int gh[NBKT];
    int b = blockIdx.x, t = threadIdx.x;
    int nbeg = b * NPB;
    int nn = min(NPB, N_NODES - nbeg);
    int cnt = bcnt[b];
    int base = ebase[b];
    const int* reg = pairs + (size_t)b * CAP;

    for (int i = t; i < NPB; i += 256) dh[i] = 0;
    if (t < NBKT) gh[t] = 0;
    __syncthreads();

    for (int j = t; j < cnt; j += 256)
        atomicAdd(&dh[reg[j] >> 17], 1);
    __syncthreads();

    int a0 = dh[2 * t];
    int a1 = dh[2 * t + 1];
    sc[t] = a0 + a1;
    __syncthreads();
    for (int off = 1; off < 256; off <<= 1) {
        int u = (t >= off) ? sc[t - off] : 0;
        __syncthreads();
        sc[t] += u;
        __syncthreads();
    }
    int e0 = sc[t] - (a0 + a1);
    int e1 = e0 + a0;
    int i0 = 2 * t, i1 = 2 * t + 1;
    if (i0 < nn) {
        deg[nbeg + i0] = a0;
        rowptr[nbeg + i0] = base + e0;
        atomicAdd(&gh[min(a0, NBKT - 1)], 1);
    }
    if (i1 < nn) {
        deg[nbeg + i1] = a1;
        rowptr[nbeg + i1] = base + e1;
        atomicAdd(&gh[min(a1, NBKT - 1)], 1);
    }
    __syncthreads();
    dh[i0] = e0;
    dh[i1] = e1;
    __syncthreads();

    for (int j = t; j < cnt; j += 256) {
        int p = reg[j];
        int r = atomicAdd(&dh[p >> 17], 1);
        csr[base + r] = p & 0x1FFFF;
    }
    __syncthreads();
    if (t < NBKT && gh[t]) atomicAdd(&gcount[t], gh[t]);
}

// ---------------------------------------------------------------------------
// gscan + bucket scatter (R11)
// ---------------------------------------------------------------------------
__global__ void gscan_kernel(const int* __restrict__ gcount, int* __restrict__ gcur) {
    if (threadIdx.x == 0) {
        int off = 0;
        for (int k = 0; k < NBKT; ++k) {
            gcur[k] = off;
            off += (gcount[k] + BPAD - 1) & ~(BPAD - 1);
        }
    }
}

__global__ void bucket_scatter_kernel(const int* __restrict__ deg,
                                      int* __restrict__ gcur,
                                      int* __restrict__ nodelist) {
    __shared__ int lh[NBKT], lbase[NBKT];
    int t = threadIdx.x;
    if (t < NBKT) lh[t] = 0;
    __syncthreads();
    int i = blockIdx.x * 256 + t;
    int k = 0, r = 0;
    bool valid = (i < N_NODES);
    if (valid) {
        k = min(deg[i], NBKT - 1);
        r = atomicAdd(&lh[k], 1);
    }
    __syncthreads();
    if (t < NBKT && lh[t]) lbase[t] = atomicAdd(&gcur[t], lh[t]);
    __syncthreads();
    if (valid) nodelist[lbase[k] + r] = i;
}

// ---------------------------------------------------------------------------
// Shared conv body: fp8 gather (64B rows, HW cvt) + bucketed matvec.
// OUTMODE 0: write f32 rows to outf (emb).
// OUTMODE 1: relu + HW fp8 encode -> outq (table for conv2).
// ---------------------------------------------------------------------------
template <int OUTMODE>
__global__ __launch_bounds__(256) void conv_fp8_kernel(
        const unsigned char* __restrict__ xq,
        const int* __restrict__ rowptr,
        const int* __restrict__ csr,
        const int* __restrict__ nodelist,
        const float* __restrict__ Wl,
        const float* __restrict__ bl,
        const float* __restrict__ Wr,
        float* __restrict__ outf,
        unsigned char* __restrict__ outq) {
    __shared__ float lds_h[BPAD][DIM + 4];
    __shared__ float lds_x[BPAD][DIM + 4];
    __shared__ int s_node[BPAD];
    __shared__ int s_d0;

    int base = blockIdx.x * BPAD;
    int node0 = nodelist[base];
    if (node0 < 0) return;

    int grp = threadIdx.x >> 3;
    int q   = threadIdx.x & 7;
    int node = nodelist[base + grp];
    bool valid = (node >= 0);

    int beg = 0, end = 0;
    if (valid) { beg = rowptr[node]; end = rowptr[node + 1]; }

    if (threadIdx.x == 0) s_d0 = min(end - beg, MAXD);
    if (q == 0) s_node[grp] = node;

    float hs[8];
#pragma unroll
    for (int j = 0; j < 8; ++j) hs[j] = 0.f;

#define QACC(a) { \
    v2f p0 = __builtin_amdgcn_cvt_pk_f32_fp8((a).x, false); \
    v2f p1 = __builtin_amdgcn_cvt_pk_f32_fp8((a).x, true); \
    v2f p2 = __builtin_amdgcn_cvt_pk_f32_fp8((a).y, false); \
    v2f p3 = __builtin_amdgcn_cvt_pk_f32_fp8((a).y, true); \
    hs[0] += p0.x; hs[1] += p0.y; hs[2] += p1.x; hs[3] += p1.y; \
    hs[4] += p2.x; hs[5] += p2.y; hs[6] += p3.x; hs[7] += p3.y; }

    int e = beg;
    for (; e + 8 <= end; e += 8) {
        int s0 = csr[e + 0], s1 = csr[e + 1], s2 = csr[e + 2], s3 = csr[e + 3];
        int s4 = csr[e + 4], s5 = csr[e + 5], s6 = csr[e + 6], s7 = csr[e + 7];
        uint2 a0 = *reinterpret_cast<const uint2*>(xq + (size_t)s0 * DIM + q * 8);
        uint2 a1 = *reinterpret_cast<const uint2*>(xq + (size_t)s1 * DIM + q * 8);
        uint2 a2 = *reinterpret_cast<const uint2*>(xq + (size_t)s2 * DIM + q * 8);
        uint2 a3 = *reinterpret_cast<const uint2*>(xq + (size_t)s3 * DIM + q * 8);
        uint2 a4 = *reinterpret_cast<const uint2*>(xq + (size_t)s4 * DIM + q * 8);
        uint2 a5 = *reinterpret_cast<const uint2*>(xq + (size_t)s5 * DIM + q * 8);
        uint2 a6 = *reinterpret_cast<const uint2*>(xq + (size_t)s6 * DIM + q * 8);
        uint2 a7 = *reinterpret_cast<const uint2*>(xq + (size_t)s7 * DIM + q * 8);
        QACC(a0) QACC(a1) QACC(a2) QACC(a3)
        QACC(a4) QACC(a5) QACC(a6) QACC(a7)
    }
    for (; e + 4 <= end; e += 4) {
        int s0 = csr[e + 0], s1 = csr[e + 1], s2 = csr[e + 2], s3 = csr[e + 3];
        uint2 a0 = *reinterpret_cast<const uint2*>(xq + (size_t)s0 * DIM + q * 8);
        uint2 a1 = *reinterpret_cast<const uint2*>(xq + (size_t)s1 * DIM + q * 8);
        uint2 a2 = *reinterpret_cast<const uint2*>(xq + (size_t)s2 * DIM + q * 8);
        uint2 a3 = *reinterpret_cast<const uint2*>(xq + (size_t)s3 * DIM + q * 8);
        QACC(a0) QACC(a1) QACC(a2) QACC(a3)
    }
    for (; e < end; ++e) {
        int s = csr[e];
        uint2 a = *reinterpret_cast<const uint2*>(xq + (size_t)s * DIM + q * 8);
        QACC(a)
    }
#undef QACC

    float xv[8];
    if (valid) {
        uint2 a = *reinterpret_cast<const uint2*>(xq + (size_t)node * DIM + q * 8);
        v2f p0 = __builtin_amdgcn_cvt_pk_f32_fp8(a.x, false);
        v2f p1 = __builtin_amdgcn_cvt_pk_f32_fp8(a.x, true);
        v2f p2 = __builtin_amdgcn_cvt_pk_f32_fp8(a.y, false);
        v2f p3 = __builtin_amdgcn_cvt_pk_f32_fp8(a.y, true);
        xv[0] = p0.x; xv[1] = p0.y; xv[2] = p1.x; xv[3] = p1.y;
        xv[4] = p2.x; xv[5] = p2.y; xv[6] = p3.x; xv[7] = p3.y;
    } else {
#pragma unroll
        for (int j = 0; j < 8; ++j) xv[j] = 0.f;
    }

    *reinterpret_cast<float4*>(&lds_h[grp][q * 8 + 0]) = make_float4(hs[0], hs[1], hs[2], hs[3]);
    *reinterpret_cast<float4*>(&lds_h[grp][q * 8 + 4]) = make_float4(hs[4], hs[5], hs[6], hs[7]);
    *reinterpret_cast<float4*>(&lds_x[grp][q * 8 + 0]) = make_float4(xv[0], xv[1], xv[2], xv[3]);
    *reinterpret_cast<float4*>(&lds_x[grp][q * 8 + 4]) = make_float4(xv[4], xv[5], xv[6], xv[7]);
    __syncthreads();

    int mgrp = threadIdx.x >> 4;
    int mq   = threadIdx.x & 15;
    int d0 = s_d0;
    const float* wl = Wl + (size_t)d0 * DIM * DIM + mq * 4;
    const float* wr = Wr + (size_t)d0 * DIM * DIM + mq * 4;
    float4 accA = *reinterpret_cast<const float4*>(bl + d0 * DIM + mq * 4);
    float4 accB = accA;

#pragma unroll 8
    for (int i = 0; i < DIM; ++i) {
        float4 wlv = *reinterpret_cast<const float4*>(wl + i * DIM);
        float4 wrv = *reinterpret_cast<const float4*>(wr + i * DIM);
        float hA = lds_h[mgrp][i],      xA = lds_x[mgrp][i];
        float hB = lds_h[mgrp + 16][i], xB = lds_x[mgrp + 16][i];
        accA.x += hA * wlv.x + xA * wrv.x;
        accA.y += hA * wlv.y + xA * wrv.y;
        accA.z += hA * wlv.z + xA * wrv.z;
        accA.w += hA * wlv.w + xA * wrv.w;
        accB.x += hB * wlv.x + xB * wrv.x;
        accB.y += hB * wlv.y + xB * wrv.y;
        accB.z += hB * wlv.z + xB * wrv.z;
        accB.w += hB * wlv.w + xB * wrv.w;
    }

    int nodeA = s_node[mgrp];
    int nodeB = s_node[mgrp + 16];
    if (OUTMODE == 0) {
        if (nodeA >= 0)
            *reinterpret_cast<float4*>(outf + (size_t)nodeA * DIM + mq * 4) = accA;
        if (nodeB >= 0)
            *reinterpret_cast<float4*>(outf + (size_t)nodeB * DIM + mq * 4) = accB;
    } else {
        if (nodeA >= 0) {
            int oq = __builtin_amdgcn_cvt_pk_fp8_f32(fmaxf(accA.x, 0.f), fmaxf(accA.y, 0.f), 0, false);
            oq = __builtin_amdgcn_cvt_pk_fp8_f32(fmaxf(accA.z, 0.f), fmaxf(accA.w, 0.f), oq, true);
            *reinterpret_cast<unsigned*>(outq + (size_t)nodeA * DIM + mq * 4) = (unsigned)oq;
        }
        if (nodeB >= 0) {
            int oq = __builtin_amdgcn_cvt_pk_fp8_f32(fmaxf(accB.x, 0.f), fmaxf(accB.y, 0.f), 0, false);
            oq = __builtin_amdgcn_cvt_pk_fp8_f32(fmaxf(accB.z, 0.f), fmaxf(accB.w, 0.f), oq, true);
            *reinterpret_cast<unsigned*>(outq + (size_t)nodeB * DIM + mq * 4) = (unsigned)oq;
        }
    }
}

// ---------------------------------------------------------------------------
// Fused global_add_pool(relu(emb)) + MLP head; one block per graph.
// ---------------------------------------------------------------------------
__global__ void pool_head_kernel(const float* __restrict__ emb,
                                 const int* __restrict__ batch,
                                 const float* __restrict__ W1,
                                 const float* __restrict__ b1,
                                 const float* __restrict__ W2,
                                 const float* __restrict__ b2,
                                 float* __restrict__ pred) {
    __shared__ float red[4][DIM];
    __shared__ float garr[DIM];
    __shared__ float hid[DIM];
    int gi = blockIdx.x;
    int w = threadIdx.x >> 6;
    int lane = threadIdx.x & 63;

    int lo = 0, hi = N_NODES;
    while (lo < hi) { int mid = (lo + hi) >> 1; if (batch[mid] < gi) lo = mid + 1; else hi = mid; }
    int beg = lo;
    hi = N_NODES;
    while (lo < hi) { int mid = (lo + hi) >> 1; if (batch[mid] < gi + 1) lo = mid + 1; else hi = mid; }
    int end = lo;

    float acc = 0.f;
    for (int n = beg + w; n < end; n += 4)
        acc += fmaxf(emb[(size_t)n * DIM + lane], 0.f);
    red[w][lane] = acc;
    __syncthreads();
    if (w == 0)
        garr[lane] = red[0][lane] + red[1][lane] + red[2][lane] + red[3][lane];
    __syncthreads();

    if (threadIdx.x < DIM) {
        int o = threadIdx.x;
        float a = b1[o];
#pragma unroll 8
        for (int i = 0; i < DIM; ++i) a += garr[i] * W1[i * DIM + o];
        hid[o] = a;
    }
    __syncthreads();
    if (threadIdx.x < ODIM) {
        int o = threadIdx.x;
        float p = b2[o];
#pragma unroll 8
        for (int i = 0; i < DIM; ++i) p += hid[i] * W2[i * ODIM + o];
        pred[(size_t)gi * ODIM + o] = p;
    }
}

extern "C" void kernel_launch(void* const* d_in, const int* in_sizes, int n_in,
                              void* d_out, int out_size, void* d_ws, size_t ws_size,
                              hipStream_t stream) {
    const float* x    = (const float*)d_in[0];
    const int* eidx   = (const int*)d_in[1];
    const int* src    = eidx;
    const int* dst    = eidx + N_EDGES;
    const int* batch  = (const int*)d_in[2];
    const float* Wl1  = (const float*)d_in[4];
    const float* bl1  = (const float*)d_in[5];
    const float* Wr1  = (const float*)d_in[6];
    const float* Wl2  = (const float*)d_in[7];
    const float* bl2  = (const float*)d_in[8];
    const float* Wr2  = (const float*)d_in[9];
    const float* W1   = (const float*)d_in[10];
    const float* b1   = (const float*)d_in[11];
    const float* W2   = (const float*)d_in[12];
    const float* b2   = (const float*)d_in[13];

    float* emb  = (float*)d_out;                          // [N_NODES, 64]
    float* pred = (float*)d_out + (size_t)N_NODES * DIM;  // [N_GRAPHS, 32]

    // Workspace
    int* bcur     = (int*)d_ws;                  // [256]
    int* ebase    = bcur + 256;                  // [256]
    int* gcount   = ebase + 256;                 // [32]
    int* gcur     = gcount + NBKT;               // [32]
    int* deg      = gcur + NBKT;                 // [100000]
    int* rowptr   = deg + N_NODES;               // [100004]
    int* nodelist = rowptr + N_NODES + 4;        // [100992]
    int* csr      = nodelist + LIST_PAD;         // [1200000]
    int* pairs    = csr + N_EDGES;               // [196*8192]
    unsigned char* xq = (unsigned char*)(pairs + NBUK * CAP);    // [N*64] fp8
    unsigned char* hq = xq + (size_t)N_NODES * DIM;              // [N*64] fp8

    prep_kernel<<<(PREP_THREADS + 255) / 256, 256, 0, stream>>>(x, xq, bcur, gcount, nodelist);
    pass1_bin_kernel<<<P1_NB, 256, 0, stream>>>(src, dst, bcur, pairs);
    escan_kernel<<<1, 256, 0, stream>>>(bcur, ebase, rowptr);
    pass2_kernel<<<NBUK, 256, 0, stream>>>(pairs, bcur, ebase, deg, rowptr, csr, gcount);
    gscan_kernel<<<1, 64, 0, stream>>>(gcount, gcur);
    bucket_scatter_kernel<<<(N_NODES + 255) / 256, 256, 0, stream>>>(deg, gcur, nodelist);

    // conv1: fp8 gather + matvec + relu -> hq (fp8 table for conv2)
    conv_fp8_kernel<1><<<CONV_BLK, 256, 0, stream>>>(xq, rowptr, csr, nodelist,
                                                     Wl1, bl1, Wr1, nullptr, hq);
    // conv2: fp8 gather + matvec -> emb (f32, pre-activation output)
    conv_fp8_kernel<0><<<CONV_BLK, 256, 0, stream>>>(hq, rowptr, csr, nodelist,
                                                     Wl2, bl2, Wr2, emb, nullptr);
    // fused pool + head
    pool_head_kernel<<<N_GRAPHS, 256, 0, stream>>>(emb, batch, W1, b1, W2, b2, pred);
}